// Round 9
// baseline (661.292 us; speedup 1.0000x reference)
//
#include <hip/hip_runtime.h>
#include <hip/hip_cooperative_groups.h>

namespace cg = cooperative_groups;

// ---------------- workspace layout (byte offsets, all 256-aligned) ----------
static constexpr size_t OFF_XT = 0;          // xT  [3][32][32][64] f32   786432 B
static constexpr size_t OFF_H1 = 786432;     // h1  [18][28][28][64]      3612672 B (dead after ph2; reused P1..P3)
static constexpr size_t OFF_H2 = 4399104;    // h2  [51][14][14][64]      2558976 B
static constexpr size_t OFF_H3 = 6958080;    // h3  [255][5][5][2][2][64] 6528000 B (pool-permuted)
static constexpr size_t OFF_H4 = 13486080;   // h4  [515][5][5][64]       3296000 B
static constexpr size_t OFF_P0 = 16782080;   // oo partial 0 [100][25][64] 640000 B
static constexpr size_t OFF_P1 = OFF_H1;            // oo partial 1 (aliases dead h1)
static constexpr size_t OFF_P2 = OFF_H1 + 640000;   // oo partial 2
static constexpr size_t OFF_P3 = OFF_H1 + 1280000;  // oo partial 3
static constexpr size_t OFF_H6 = 17422080;   // h6T [120][64] PRE-ACT     30720 B (zeroed ph0; atomicAdd ph6)
static constexpr size_t OFF_H7 = 17452800;   // h7T [84][64]              21504 B
static constexpr size_t OFF_M1 = 17474304;   // int src1[51][4]           1024 B
static constexpr size_t OFF_M2 = 17475328;   // Meta2[536]                8704 B
static constexpr size_t OFF_W2 = 17484032;   // float W2[536][51]         109568 B

struct Meta2 { int g; int special; float wj; int valid; };

struct Params {
  const float *x, *dw1_w, *dw1_b, *pc1_w, *pc1_b, *dw2_w, *dw2_b,
              *pc2_w, *pc2_b, *oo_w, *oo_b, *fc1_w, *fc1_b,
              *fc2_w, *fc2_b, *fc3_w, *fc3_b;
  float* ws;
  float* out;
};

// enumerate pc1 groups in build_perm order (tiny: 51 entries, F=6 ncpf=3)
__device__ inline void scan_ijk(int F, int ncpf, int g, int& oi, int& oj, int& ok) {
  int cnt = 0;
  for (int i = 0; i < F; ++i)
    for (int j = 0; j < ncpf; ++j) {
      int ks = (j == 0) ? i : i + 1;
      for (int k = ks; k < F; ++k) {
        if (cnt == g) { oi = i; oj = j; ok = k; return; }
        ++cnt;
      }
    }
  oi = 0; oj = 0; ok = 0;
}

// ONE cooperative kernel: 9 former dispatches -> 8 grid.sync()s.
// grid(512) block(256): 2048 waves, 2 blocks/CU co-resident.
__global__ void __launch_bounds__(256, 4) mega(Params P) {
  cg::grid_group grid = cg::this_grid();
  float* ws = P.ws;
  __shared__ float t[64][33];                 // phase 0 transpose staging
  int tid = threadIdx.x;
  int lane = tid & 63;
  int wvb = __builtin_amdgcn_readfirstlane(tid >> 6);   // scalar wave-in-block
  int wid = blockIdx.x * 4 + wvb;             // scalar global wave id, 0..2047
  const int NW = 512 * 4;

  // ---------------- phase 0: setup (transpose, metadata, W2, zero h6) ------
  {
    int bx = blockIdx.x;
    if (bx < 96) {
      int c = bx >> 5, y = bx & 31;
      for (int r = 0; r < 8; ++r) {
        int b = r * 8 + (tid >> 5), xx = tid & 31;
        t[b][xx] = P.x[((b * 3 + c) * 32 + y) * 32 + xx];
      }
      __syncthreads();
      float* xT = ws + OFF_XT / 4;
      for (int r = 0; r < 8; ++r) {
        int xx = r * 4 + (tid >> 6), b = tid & 63;
        xT[((c * 32 + y) * 32 + xx) * 64 + b] = t[b][xx];
      }
    } else if (bx == 96) {
      if (tid < 51) {
        int i, j, k; scan_ijk(6, 3, tid, i, j, k);
        int* src1 = (int*)((char*)ws + OFF_M1);
        for (int p = 0; p < 3; ++p)
          src1[tid * 4 + p] = (p == j) ? (i * 3 + j) : (k * 3 + p);
      }
    } else if (bx < 204) {
      int idx = (bx - 97) * 256 + tid;       // one thread per (s,p), 536*51
      if (idx < 536 * 51) {
        int s = idx / 51, p = idx - s * 51;
        int k, base;
        if (s < 8)        { k = 0; base = 0; }
        else if (s < 64)  { k = 1; base = 8; }
        else if (s < 168) { k = 2; base = 64; }
        else if (s < 328) { k = 3; base = 168; }
        else              { k = 4; base = 328; }
        int id2 = s - base;
        int cnt = 51 * k + 1;
        Meta2* m2 = (Meta2*)((char*)ws + OFF_M2);
        float* W2 = (float*)((char*)ws + OFF_W2);
        if (id2 < cnt) {
          int i, j;
          if (id2 <= k) { i = id2; j = 0; }
          else { int t2 = id2 - (k + 1); i = t2 / 50; j = t2 - i * 50 + 1; }
          int off = 205 * i - 51 * ((i * (i - 1)) >> 1);
          int g = (j == 0) ? (off + (k - i))
                           : (off + (5 - i) + (j - 1) * (4 - i) + (k - i - 1));
          W2[s * 51 + p] = (p == j) ? 0.f : P.pc2_w[g * 51 + p];
          if (p == 0) {
            m2[s].g = g; m2[s].special = i * 51 + j;
            m2[s].wj = P.pc2_w[g * 51 + j]; m2[s].valid = 1;
          }
        } else {
          W2[s * 51 + p] = 0.f;
          if (p == 0) { m2[s].g = 0; m2[s].special = 0; m2[s].wj = 0.f; m2[s].valid = 0; }
        }
      }
    } else if (bx < 234) {
      int idx = (bx - 204) * 256 + tid;      // zero h6: 7680 floats
      if (idx < 7680) (ws + OFF_H6 / 4)[idx] = 0.f;
    }
  }
  grid.sync();

  // ---------------- phase 1: dw1 5x5 groups=3 (14112 wave-tasks) -----------
  {
    const float* xT = ws + OFF_XT / 4;
    float* h1 = ws + OFF_H1 / 4;
    for (int tk = wid; tk < 14112; tk += NW) {
      int o = tk / 784, pos = tk - o * 784;
      int y = pos / 28, xo = pos - y * 28;
      int c = o / 6;
      float acc = P.dw1_b[o];
      #pragma unroll
      for (int ky = 0; ky < 5; ++ky)
        #pragma unroll
        for (int kx = 0; kx < 5; ++kx)
          acc = fmaf(xT[((c * 32 + y + ky) * 32 + xo + kx) * 64 + lane],
                     P.dw1_w[o * 25 + ky * 5 + kx], acc);
      h1[((o * 28 + y) * 28 + xo) * 64 + lane] = acc;
    }
  }
  grid.sync();

  // ---------------- phase 2: pc1 gather+relu+pool (9996 wave-tasks) --------
  {
    const float* h1 = ws + OFF_H1 / 4;
    const int* src1 = (const int*)((const char*)ws + OFF_M1);
    float* h2 = ws + OFF_H2 / 4;
    for (int tk = wid; tk < 9996; tk += NW) {
      int g = tk / 196, pos = tk - g * 196;
      int py = pos / 14, px = pos - py * 14;
      int s0 = src1[g * 4 + 0], s1 = src1[g * 4 + 1], s2 = src1[g * 4 + 2];
      float w0 = P.pc1_w[g * 3 + 0], w1 = P.pc1_w[g * 3 + 1], w2 = P.pc1_w[g * 3 + 2];
      float bb = P.pc1_b[g];
      float m = 0.f;
      #pragma unroll
      for (int dy = 0; dy < 2; ++dy)
        #pragma unroll
        for (int dx = 0; dx < 2; ++dx) {
          int y = py * 2 + dy, xx = px * 2 + dx;
          float a = bb;
          a = fmaf(h1[((s0 * 28 + y) * 28 + xx) * 64 + lane], w0, a);
          a = fmaf(h1[((s1 * 28 + y) * 28 + xx) * 64 + lane], w1, a);
          a = fmaf(h1[((s2 * 28 + y) * 28 + xx) * 64 + lane], w2, a);
          m = fmaxf(m, a);
        }
      h2[((g * 14 + py) * 14 + px) * 64 + lane] = m;
    }
  }
  grid.sync();

  // ---------------- phase 3: dw2 5x5 groups=51, pool-permuted (25500) ------
  {
    const float* h2 = ws + OFF_H2 / 4;
    float* h3 = ws + OFF_H3 / 4;
    for (int tk = wid; tk < 25500; tk += NW) {
      int o = tk / 100, pos = tk - o * 100;
      int y = pos / 10, xo = pos - y * 10;
      int c = o / 5;
      float acc = P.dw2_b[o];
      #pragma unroll
      for (int ky = 0; ky < 5; ++ky)
        #pragma unroll
        for (int kx = 0; kx < 5; ++kx)
          acc = fmaf(h2[((c * 14 + y + ky) * 14 + xo + kx) * 64 + lane],
                     P.dw2_w[o * 25 + ky * 5 + kx], acc);
      int py = y >> 1, dy = y & 1, px = xo >> 1, dx = xo & 1;
      h3[((o * 25 + py * 5 + px) * 4 + dy * 2 + dx) * 64 + lane] = acc;
    }
  }
  grid.sync();

  // ---------------- phase 4: pc2 dense+rank-1, bias+relu+pool (6700) -------
  // task = (pyx, slot-pair): consecutive wids share pyx -> L1 reuse of h3.
  {
    const float* h3 = ws + OFF_H3 / 4;
    const float* W2 = (const float*)((const char*)ws + OFF_W2);
    const Meta2* m2 = (const Meta2*)((const char*)ws + OFF_M2);
    float* h4 = ws + OFF_H4 / 4;
    for (int tk = wid; tk < 6700; tk += NW) {
      int pyx = tk / 268, sp = tk - pyx * 268;
      int s0 = sp * 2;
      int k;
      if (s0 < 8) k = 0; else if (s0 < 64) k = 1; else if (s0 < 168) k = 2;
      else if (s0 < 328) k = 3; else k = 4;
      float acc[2][4];
      #pragma unroll
      for (int m = 0; m < 2; ++m)
        #pragma unroll
        for (int q = 0; q < 4; ++q) acc[m][q] = 0.f;
      const float* hb = h3 + (size_t)(k * 51 * 100 + pyx * 4) * 64 + lane;
      const float* wr0 = W2 + (s0 + 0) * 51;
      const float* wr1 = W2 + (s0 + 1) * 51;
      for (int p = 0; p < 51; ++p) {
        float v0 = hb[p * 6400 + 0];
        float v1 = hb[p * 6400 + 64];
        float v2 = hb[p * 6400 + 128];
        float v3 = hb[p * 6400 + 192];
        float wa = wr0[p], wb = wr1[p];     // scalar s_loads
        acc[0][0] = fmaf(v0, wa, acc[0][0]);
        acc[0][1] = fmaf(v1, wa, acc[0][1]);
        acc[0][2] = fmaf(v2, wa, acc[0][2]);
        acc[0][3] = fmaf(v3, wa, acc[0][3]);
        acc[1][0] = fmaf(v0, wb, acc[1][0]);
        acc[1][1] = fmaf(v1, wb, acc[1][1]);
        acc[1][2] = fmaf(v2, wb, acc[1][2]);
        acc[1][3] = fmaf(v3, wb, acc[1][3]);
      }
      #pragma unroll
      for (int m = 0; m < 2; ++m) {
        Meta2 mm = m2[s0 + m];
        if (!mm.valid) continue;           // scalar branch
        const float* hs = h3 + (size_t)(mm.special * 100 + pyx * 4) * 64 + lane;
        float bb = P.pc2_b[mm.g];
        float r0 = fmaf(hs[0],   mm.wj, acc[m][0]) + bb;
        float r1 = fmaf(hs[64],  mm.wj, acc[m][1]) + bb;
        float r2 = fmaf(hs[128], mm.wj, acc[m][2]) + bb;
        float r3 = fmaf(hs[192], mm.wj, acc[m][3]) + bb;
        float r = fmaxf(fmaxf(r0, r1), fmaxf(r2, r3));
        h4[(mm.g * 25 + pyx) * 64 + lane] = fmaxf(r, 0.f);
      }
    }
  }
  grid.sync();

  // ---------------- phase 5: oo partials, 4-way K split (2500 tasks) -------
  {
    const float* h4 = ws + OFF_H4 / 4;
    for (int tk = wid; tk < 2500; tk += NW) {
      int ks = tk / 625, rem = tk - ks * 625;
      int og = rem / 25, pyx = rem - og * 25;
      int kb = ks * 128 + (ks < 3 ? ks : 3);     // [0,129)[129,258)[258,387)[387,515)
      int kn = 128 + (ks < 3 ? 1 : 0);
      const float* w0 = P.oo_w + (og * 4 + 0) * 515;
      const float* w1 = P.oo_w + (og * 4 + 1) * 515;
      const float* w2 = P.oo_w + (og * 4 + 2) * 515;
      const float* w3 = P.oo_w + (og * 4 + 3) * 515;
      const float* hp = h4 + pyx * 64 + lane;
      float a0 = 0.f, a1 = 0.f, a2 = 0.f, a3 = 0.f;
      #pragma unroll 4
      for (int i = 0; i < kn; ++i) {
        int c = kb + i;
        float v = hp[c * 1600];
        a0 = fmaf(v, w0[c], a0);
        a1 = fmaf(v, w1[c], a1);
        a2 = fmaf(v, w2[c], a2);
        a3 = fmaf(v, w3[c], a3);
      }
      float* pp = ws + (ks == 0 ? OFF_P0 : ks == 1 ? OFF_P1 : ks == 2 ? OFF_P2 : OFF_P3) / 4;
      pp[((og * 4 + 0) * 25 + pyx) * 64 + lane] = a0;
      pp[((og * 4 + 1) * 25 + pyx) * 64 + lane] = a1;
      pp[((og * 4 + 2) * 25 + pyx) * 64 + lane] = a2;
      pp[((og * 4 + 3) * 25 + pyx) * 64 + lane] = a3;
    }
  }
  grid.sync();

  // ---------------- phase 6: fc1 partials -> atomicAdd h6 (960 tasks) ------
  {
    const float* p0 = ws + OFF_P0 / 4;
    const float* p1 = ws + OFF_P1 / 4;
    const float* p2 = ws + OFF_P2 / 4;
    const float* p3 = ws + OFF_P3 / 4;
    float* h6 = ws + OFF_H6 / 4;
    for (int tk = wid; tk < 960; tk += NW) {
      int og = tk / 32, ks = tk - og * 32;
      int kb = ks * 78 + (ks < 4 ? ks : 4);      // sums to 2500
      int kn = 78 + (ks < 4 ? 1 : 0);
      const float* w0 = P.fc1_w + (og * 4 + 0) * 2500;
      const float* w1 = P.fc1_w + (og * 4 + 1) * 2500;
      const float* w2 = P.fc1_w + (og * 4 + 2) * 2500;
      const float* w3 = P.fc1_w + (og * 4 + 3) * 2500;
      float a0 = 0.f, a1 = 0.f, a2 = 0.f, a3 = 0.f;
      #pragma unroll 2
      for (int i = 0; i < kn; ++i) {
        int k = kb + i;
        float v = p0[k * 64 + lane] + p1[k * 64 + lane] +
                  p2[k * 64 + lane] + p3[k * 64 + lane] + P.oo_b[k / 25];
        v = fmaxf(v, 0.f);
        a0 = fmaf(v, w0[k], a0);
        a1 = fmaf(v, w1[k], a1);
        a2 = fmaf(v, w2[k], a2);
        a3 = fmaf(v, w3[k], a3);
      }
      atomicAdd(&h6[(og * 4 + 0) * 64 + lane], a0);
      atomicAdd(&h6[(og * 4 + 1) * 64 + lane], a1);
      atomicAdd(&h6[(og * 4 + 2) * 64 + lane], a2);
      atomicAdd(&h6[(og * 4 + 3) * 64 + lane], a3);
    }
  }
  grid.sync();

  // ---------------- phase 7: fc2 + relu (84 wave-tasks) --------------------
  {
    const float* h6 = ws + OFF_H6 / 4;
    float* h7 = ws + OFF_H7 / 4;
    for (int tk = wid; tk < 84; tk += NW) {
      int o = tk;
      float acc = P.fc2_b[o];
      #pragma unroll 4
      for (int i = 0; i < 120; ++i) {
        float v = fmaxf(h6[i * 64 + lane] + P.fc1_b[i], 0.f);
        acc = fmaf(v, P.fc2_w[o * 120 + i], acc);
      }
      h7[o * 64 + lane] = fmaxf(acc, 0.f);
    }
  }
  grid.sync();

  // ---------------- phase 8: fc3 -> out [64][10] (10 wave-tasks) -----------
  {
    const float* h7 = ws + OFF_H7 / 4;
    for (int tk = wid; tk < 10; tk += NW) {
      int o = tk;
      float acc = P.fc3_b[o];
      #pragma unroll 4
      for (int i = 0; i < 84; ++i)
        acc = fmaf(h7[i * 64 + lane], P.fc3_w[o * 84 + i], acc);
      P.out[lane * 10 + o] = acc;
    }
  }
}

extern "C" void kernel_launch(void* const* d_in, const int* in_sizes, int n_in,
                              void* d_out, int out_size, void* d_ws, size_t ws_size,
                              hipStream_t stream) {
  Params p;
  p.x     = (const float*)d_in[0];
  p.dw1_w = (const float*)d_in[1];
  p.dw1_b = (const float*)d_in[2];
  p.pc1_w = (const float*)d_in[3];
  p.pc1_b = (const float*)d_in[4];
  p.dw2_w = (const float*)d_in[5];
  p.dw2_b = (const float*)d_in[6];
  p.pc2_w = (const float*)d_in[7];
  p.pc2_b = (const float*)d_in[8];
  p.oo_w  = (const float*)d_in[9];
  p.oo_b  = (const float*)d_in[10];
  p.fc1_w = (const float*)d_in[11];
  p.fc1_b = (const float*)d_in[12];
  p.fc2_w = (const float*)d_in[13];
  p.fc2_b = (const float*)d_in[14];
  p.fc3_w = (const float*)d_in[15];
  p.fc3_b = (const float*)d_in[16];
  p.ws  = (float*)d_ws;
  p.out = (float*)d_out;

  void* args[] = { &p };
  hipLaunchCooperativeKernel((const void*)&mega, dim3(512), dim3(256),
                             args, 0, stream);
}

// Round 10
// 150.324 us; speedup vs baseline: 4.3991x; 4.3991x over previous
//
#include <hip/hip_runtime.h>

// ---------------- workspace layout (byte offsets, all 256-aligned) ----------
static constexpr size_t OFF_XT = 0;          // xT  [3][32][32][64] f32   786432 B
static constexpr size_t OFF_H1 = 786432;     // h1  [18][28][28][64]      3612672 B  (dead after k2; reused as h5b)
static constexpr size_t OFF_H2 = 4399104;    // h2  [51][14][14][64]      2558976 B
static constexpr size_t OFF_H3 = 6958080;    // h3  [255][5][5][2][2][64] 6528000 B  (pool-permuted)
static constexpr size_t OFF_H4 = 13486080;   // h4  [515][5][5][64]       3296000 B
static constexpr size_t OFF_H5 = 16782080;   // h5a [2500][64] PARTIAL    640000 B
static constexpr size_t OFF_H5B = OFF_H1;    // h5b [2500][64] PARTIAL    (aliases dead h1)
static constexpr size_t OFF_H6 = 17422080;   // h6T [120][64] PRE-ACT     30720 B (zeroed in k0; atomicAdd in k6)
static constexpr size_t OFF_H7 = 17452800;   // h7T [84][64]              21504 B
static constexpr size_t OFF_M1 = 17474304;   // int src1[51][4]           1024 B
static constexpr size_t OFF_M2 = 17475328;   // Meta2[536]                8704 B
static constexpr size_t OFF_W2 = 17484032;   // float W2[536][51]         109568 B
// total ~17.6 MB

struct Meta2 { int g; int special; float wj; int valid; };

// enumerate pc1 groups in build_perm order (tiny: 51 entries, F=6 ncpf=3)
__device__ inline void scan_ijk(int F, int ncpf, int g, int& oi, int& oj, int& ok) {
  int cnt = 0;
  for (int i = 0; i < F; ++i)
    for (int j = 0; j < ncpf; ++j) {
      int ks = (j == 0) ? i : i + 1;
      for (int k = ks; k < F; ++k) {
        if (cnt == g) { oi = i; oj = j; ok = k; return; }
        ++cnt;
      }
    }
  oi = 0; oj = 0; ok = 0;
}

__device__ inline float4 f4fma(float4 v, float w, float4 a) {
  a.x = fmaf(v.x, w, a.x); a.y = fmaf(v.y, w, a.y);
  a.z = fmaf(v.z, w, a.z); a.w = fmaf(v.w, w, a.w);
  return a;
}

// K0: blocks 0..95   : transpose x [64][3][32][32] -> xT [3][32][32][64]
//     block  96      : pc1 gather metadata (51 groups x 3 srcs)
//     blocks 97..203 : pc2 metadata + densified W2, one thread per (slot,p)
//     blocks 204..233: zero h6 (fc1 atomicAdd accumulator)
__global__ void k0_setup(const float* __restrict__ x, const float* __restrict__ pc2_w,
                         float* ws) {
  int bx = blockIdx.x, tid = threadIdx.x;
  if (bx < 96) {
    __shared__ float t[64][33];
    int c = bx >> 5, y = bx & 31;
    for (int r = 0; r < 8; ++r) {
      int b = r * 8 + (tid >> 5), xx = tid & 31;
      t[b][xx] = x[((b * 3 + c) * 32 + y) * 32 + xx];
    }
    __syncthreads();
    float* xT = ws + OFF_XT / 4;
    for (int r = 0; r < 8; ++r) {
      int xx = r * 4 + (tid >> 6), b = tid & 63;
      xT[((c * 32 + y) * 32 + xx) * 64 + b] = t[b][xx];
    }
  } else if (bx == 96) {
    if (tid < 51) {
      int i, j, k; scan_ijk(6, 3, tid, i, j, k);
      int* src1 = (int*)((char*)ws + OFF_M1);
      for (int p = 0; p < 3; ++p)
        src1[tid * 4 + p] = (p == j) ? (i * 3 + j) : (k * 3 + p);
    }
  } else if (bx < 204) {
    int idx = (bx - 97) * 256 + tid;     // one thread per (s,p), 536*51 = 27336
    if (idx < 536 * 51) {
      int s = idx / 51, p = idx - s * 51;
      int k, base;
      if (s < 8)        { k = 0; base = 0; }
      else if (s < 64)  { k = 1; base = 8; }
      else if (s < 168) { k = 2; base = 64; }
      else if (s < 328) { k = 3; base = 168; }
      else              { k = 4; base = 328; }
      int id2 = s - base;
      int cnt = 51 * k + 1;              // groups using contiguous block k
      Meta2* m2 = (Meta2*)((char*)ws + OFF_M2);
      float* W2 = (float*)((char*)ws + OFF_W2);
      if (id2 < cnt) {
        int i, j;
        if (id2 <= k) { i = id2; j = 0; }
        else { int t2 = id2 - (k + 1); i = t2 / 50; j = t2 - i * 50 + 1; }
        int off = 205 * i - 51 * ((i * (i - 1)) >> 1);
        int g = (j == 0) ? (off + (k - i))
                         : (off + (5 - i) + (j - 1) * (4 - i) + (k - i - 1));
        W2[s * 51 + p] = (p == j) ? 0.f : pc2_w[g * 51 + p];
        if (p == 0) {
          m2[s].g = g; m2[s].special = i * 51 + j;
          m2[s].wj = pc2_w[g * 51 + j]; m2[s].valid = 1;
        }
      } else {
        W2[s * 51 + p] = 0.f;
        if (p == 0) { m2[s].g = 0; m2[s].special = 0; m2[s].wj = 0.f; m2[s].valid = 0; }
      }
    }
  } else {
    int idx = (bx - 204) * 256 + tid;    // zero h6: 120*64 = 7680 floats
    if (idx < 7680) (ws + OFF_H6 / 4)[idx] = 0.f;
  }
}

// K1: dw1 5x5, groups=3. FLOAT4 over batch: each wave does 4 consecutive xo;
//     lane = (xo_sub = l>>4, batch4 = (l&15)*4). 25 dwordx4 loads vs 100 dword.
//     tasks = 18 o x 28 y x 7 xc = 3528. grid(882) block(64,4)
__global__ void __launch_bounds__(256) k1_dw1(const float* __restrict__ w,
                                              const float* __restrict__ bias, float* ws) {
  const float* xT = ws + OFF_XT / 4;
  float* h1 = ws + OFF_H1 / 4;
  int task = blockIdx.x * 4 + __builtin_amdgcn_readfirstlane(threadIdx.y);
  int l = threadIdx.x;
  int sub = l >> 4, b4 = (l & 15) * 4;
  int o = task / 196, rem = task - o * 196;
  int y = rem / 7, xo = (rem - y * 7) * 4 + sub;
  int c = o / 6;
  float bb = bias[o];
  float4 acc = {bb, bb, bb, bb};
  const float* src = xT + ((c * 32 + y) * 32 + xo) * 64 + b4;
  #pragma unroll
  for (int ky = 0; ky < 5; ++ky)
    #pragma unroll
    for (int kx = 0; kx < 5; ++kx) {
      float4 v = *(const float4*)(src + (ky * 32 + kx) * 64);
      acc = f4fma(v, w[o * 25 + ky * 5 + kx], acc);
    }
  *(float4*)(h1 + ((o * 28 + y) * 28 + xo) * 64 + b4) = acc;
}

// K2: pc1 gather+relu+pool, FLOAT4 over batch. 4 pooled positions per wave.
//     tasks = 51 g x 49 chunks = 2499. grid(625) block(64,4), guard.
__global__ void __launch_bounds__(256) k2_pc1(const float* __restrict__ w,
                                              const float* __restrict__ bias, float* ws) {
  const float* h1 = ws + OFF_H1 / 4;
  const int* src1 = (const int*)((const char*)ws + OFF_M1);
  float* h2 = ws + OFF_H2 / 4;
  int task = blockIdx.x * 4 + __builtin_amdgcn_readfirstlane(threadIdx.y);
  if (task >= 2499) return;
  int l = threadIdx.x;
  int sub = l >> 4, b4 = (l & 15) * 4;
  int g = task / 49, pc = task - g * 49;
  int pp = pc * 4 + sub;               // pooled position 0..195
  int py = pp / 14, px = pp - py * 14;
  int s0 = src1[g * 4 + 0], s1 = src1[g * 4 + 1], s2 = src1[g * 4 + 2];
  float w0 = w[g * 3 + 0], w1 = w[g * 3 + 1], w2 = w[g * 3 + 2], bb = bias[g];
  float4 m = {0.f, 0.f, 0.f, 0.f};
  #pragma unroll
  for (int dy = 0; dy < 2; ++dy)
    #pragma unroll
    for (int dx = 0; dx < 2; ++dx) {
      int y = py * 2 + dy, xx = px * 2 + dx;
      float4 a = {bb, bb, bb, bb};
      a = f4fma(*(const float4*)(h1 + ((s0 * 28 + y) * 28 + xx) * 64 + b4), w0, a);
      a = f4fma(*(const float4*)(h1 + ((s1 * 28 + y) * 28 + xx) * 64 + b4), w1, a);
      a = f4fma(*(const float4*)(h1 + ((s2 * 28 + y) * 28 + xx) * 64 + b4), w2, a);
      m.x = fmaxf(m.x, a.x); m.y = fmaxf(m.y, a.y);
      m.z = fmaxf(m.z, a.z); m.w = fmaxf(m.w, a.w);
    }
  *(float4*)(h2 + ((g * 14 + py) * 14 + px) * 64 + b4) = m;
}

// K3: dw2 5x5 groups=51, pool-permuted out, FLOAT4 over batch. 4 positions/wave.
//     tasks = 255 o x 25 chunks = 6375. grid(1594) block(64,4), guard.
__global__ void __launch_bounds__(256) k3_dw2(const float* __restrict__ w,
                                              const float* __restrict__ bias, float* ws) {
  const float* h2 = ws + OFF_H2 / 4;
  float* h3 = ws + OFF_H3 / 4;
  int task = blockIdx.x * 4 + __builtin_amdgcn_readfirstlane(threadIdx.y);
  if (task >= 6375) return;
  int l = threadIdx.x;
  int sub = l >> 4, b4 = (l & 15) * 4;
  int o = task / 25, pc = task - o * 25;
  int p = pc * 4 + sub;                // position 0..99
  int y = p / 10, xo = p - y * 10;
  int c = o / 5;
  float bb = bias[o];
  float4 acc = {bb, bb, bb, bb};
  const float* src = h2 + ((c * 14 + y) * 14 + xo) * 64 + b4;
  #pragma unroll
  for (int ky = 0; ky < 5; ++ky)
    #pragma unroll
    for (int kx = 0; kx < 5; ++kx) {
      float4 v = *(const float4*)(src + (ky * 14 + kx) * 64);
      acc = f4fma(v, w[o * 25 + ky * 5 + kx], acc);
    }
  int py = y >> 1, dy = y & 1, px = xo >> 1, dx = xo & 1;
  *(float4*)(h3 + ((o * 25 + py * 5 + px) * 4 + dy * 2 + dx) * 64 + b4) = acc;
}

// K4: pc2 = dense 51-dot + rank-1 correction, bias+relu+pool. block(64,4):
//     4 waves share pyx (L1 reuse), 2 slots/wave, wv readfirstlane-scalarized.
__global__ void __launch_bounds__(256) k4_pc2(const float* __restrict__ bias, float* ws) {
  const float* h3 = ws + OFF_H3 / 4;
  const float* W2 = (const float*)((const char*)ws + OFF_W2);
  const Meta2* m2 = (const Meta2*)((const char*)ws + OFF_M2);
  float* h4 = ws + OFF_H4 / 4;
  int b = threadIdx.x;
  int wv = __builtin_amdgcn_readfirstlane(threadIdx.y);  // scalar wave id
  int pyx = blockIdx.x;          // pooled position, 0..24
  int chunk = blockIdx.y;        // 0..66
  int k;
  if (chunk < 1) k = 0; else if (chunk < 8) k = 1; else if (chunk < 21) k = 2;
  else if (chunk < 41) k = 3; else k = 4;
  int s0 = chunk * 8 + wv * 2;   // this wave's 2 slots (scalar)
  float acc[2][4];
  #pragma unroll
  for (int m = 0; m < 2; ++m)
    #pragma unroll
    for (int q = 0; q < 4; ++q) acc[m][q] = 0.f;
  const float* hb = h3 + (size_t)(k * 51 * 100 + pyx * 4) * 64 + b;  // ch stride 6400
  const float* wr0 = W2 + (s0 + 0) * 51;
  const float* wr1 = W2 + (s0 + 1) * 51;
  for (int p = 0; p < 51; ++p) {
    float v0 = hb[p * 6400 + 0];
    float v1 = hb[p * 6400 + 64];
    float v2 = hb[p * 6400 + 128];
    float v3 = hb[p * 6400 + 192];
    float wa = wr0[p], wb = wr1[p];     // scalar s_loads
    acc[0][0] = fmaf(v0, wa, acc[0][0]);
    acc[0][1] = fmaf(v1, wa, acc[0][1]);
    acc[0][2] = fmaf(v2, wa, acc[0][2]);
    acc[0][3] = fmaf(v3, wa, acc[0][3]);
    acc[1][0] = fmaf(v0, wb, acc[1][0]);
    acc[1][1] = fmaf(v1, wb, acc[1][1]);
    acc[1][2] = fmaf(v2, wb, acc[1][2]);
    acc[1][3] = fmaf(v3, wb, acc[1][3]);
  }
  #pragma unroll
  for (int m = 0; m < 2; ++m) {
    Meta2 mm = m2[s0 + m];
    if (!mm.valid) continue;             // scalar branch
    const float* hs = h3 + (size_t)(mm.special * 100 + pyx * 4) * 64 + b;
    float bb = bias[mm.g];
    float r0 = fmaf(hs[0],   mm.wj, acc[m][0]) + bb;
    float r1 = fmaf(hs[64],  mm.wj, acc[m][1]) + bb;
    float r2 = fmaf(hs[128], mm.wj, acc[m][2]) + bb;
    float r3 = fmaf(hs[192], mm.wj, acc[m][3]) + bb;
    float r = fmaxf(fmaxf(r0, r1), fmaxf(r2, r3));
    h4[(mm.g * 25 + pyx) * 64 + b] = fmaxf(r, 0.f);
  }
}

// K5: oo partials (515->100). grid(25,25,2) block(64,4), base scalarized.
__global__ void __launch_bounds__(256) k5_oo(const float* __restrict__ w, float* ws) {
  const float* h4 = ws + OFF_H4 / 4;
  __shared__ float red[4][4][64];
  int lane = threadIdx.x;
  int wv = __builtin_amdgcn_readfirstlane(threadIdx.y);
  int pyx = blockIdx.x, og = blockIdx.y, ks = blockIdx.z;
  int kb = ks ? 258 : 0;                 // K halves: [0,258) / [258,515)
  int kn = ks ? 257 : 258;
  int q = kn >> 2, r = kn & 3;
  int base = __builtin_amdgcn_readfirstlane(kb + wv * q + (wv < r ? wv : r));
  int n = q + (wv < r ? 1 : 0);          // 64..65 iters per wave
  const float* w0 = w + (og * 4 + 0) * 515;
  const float* w1 = w + (og * 4 + 1) * 515;
  const float* w2 = w + (og * 4 + 2) * 515;
  const float* w3 = w + (og * 4 + 3) * 515;
  const float* hp = h4 + pyx * 64 + lane;
  float a0 = 0.f, a1 = 0.f, a2 = 0.f, a3 = 0.f;
  #pragma unroll 4
  for (int i = 0; i < n; ++i) {
    int c = base + i;
    float v = hp[c * 1600];
    a0 = fmaf(v, w0[c], a0);
    a1 = fmaf(v, w1[c], a1);
    a2 = fmaf(v, w2[c], a2);
    a3 = fmaf(v, w3[c], a3);
  }
  red[wv][0][lane] = a0; red[wv][1][lane] = a1;
  red[wv][2][lane] = a2; red[wv][3][lane] = a3;
  __syncthreads();
  if (wv == 0) {
    float* h5p = ws + (ks ? OFF_H5B : OFF_H5) / 4;
    #pragma unroll
    for (int m = 0; m < 4; ++m) {
      float s = red[0][m][lane] + red[1][m][lane] + red[2][m][lane] + red[3][m][lane];
      h5p[((og * 4 + m) * 25 + pyx) * 64 + lane] = s;
    }
  }
}

// K6: fc1 partials. grid(30,16) block(64,4), base scalarized; atomicAdd h6.
__global__ void __launch_bounds__(256) k6_fc1(const float* __restrict__ w,
                                              const float* __restrict__ oo_b, float* ws) {
  const float* h5a = ws + OFF_H5 / 4;
  const float* h5b = ws + OFF_H5B / 4;
  float* h6 = ws + OFF_H6 / 4;
  __shared__ float red[4][4][64];
  int lane = threadIdx.x;
  int wv = __builtin_amdgcn_readfirstlane(threadIdx.y);
  int og = blockIdx.x, ks = blockIdx.y;
  int kb = ks * 156 + (ks < 4 ? ks : 4);       // block k-base
  int kn = 156 + (ks < 4 ? 1 : 0);             // block k-count (sums to 2500)
  int q = kn >> 2, r = kn & 3;
  int base = __builtin_amdgcn_readfirstlane(kb + wv * q + (wv < r ? wv : r));
  int n = q + (wv < r ? 1 : 0);                // wave k-count (~39)
  const float* w0 = w + (og * 4 + 0) * 2500;
  const float* w1 = w + (og * 4 + 1) * 2500;
  const float* w2 = w + (og * 4 + 2) * 2500;
  const float* w3 = w + (og * 4 + 3) * 2500;
  float a0 = 0.f, a1 = 0.f, a2 = 0.f, a3 = 0.f;
  #pragma unroll 4
  for (int i = 0; i < n; ++i) {
    int k = base + i;
    float v = fmaxf(h5a[k * 64 + lane] + h5b[k * 64 + lane] + oo_b[k / 25], 0.f);
    a0 = fmaf(v, w0[k], a0);
    a1 = fmaf(v, w1[k], a1);
    a2 = fmaf(v, w2[k], a2);
    a3 = fmaf(v, w3[k], a3);
  }
  red[wv][0][lane] = a0; red[wv][1][lane] = a1;
  red[wv][2][lane] = a2; red[wv][3][lane] = a3;
  __syncthreads();
  if (wv == 0) {
    #pragma unroll
    for (int m = 0; m < 4; ++m) {
      float s = red[0][m][lane] + red[1][m][lane] + red[2][m][lane] + red[3][m][lane];
      atomicAdd(&h6[(og * 4 + m) * 64 + lane], s);
    }
  }
}

// K7: fc2 (120->84) + relu; applies relu(h6+fc1_b) inline. grid(84) block(256).
__global__ void __launch_bounds__(256) k7_fc2(const float* __restrict__ w,
                                              const float* __restrict__ fc1_b,
                                              const float* __restrict__ bias, float* ws) {
  const float* h6 = ws + OFF_H6 / 4;
  float* h7 = ws + OFF_H7 / 4;
  __shared__ float red[4][64];
  int lane = threadIdx.x & 63, wv = threadIdx.x >> 6;
  int o = blockIdx.x;
  float acc = 0.f;
  int i0 = wv * 30;
  #pragma unroll 5
  for (int i = i0; i < i0 + 30; ++i) {
    float v = fmaxf(h6[i * 64 + lane] + fc1_b[i], 0.f);
    acc = fmaf(v, w[o * 120 + i], acc);
  }
  red[wv][lane] = acc;
  __syncthreads();
  if (threadIdx.x < 64) {
    float s = red[0][lane] + red[1][lane] + red[2][lane] + red[3][lane] + bias[o];
    h7[o * 64 + lane] = fmaxf(s, 0.f);
  }
}

// K8: fc3 (84->10), writes d_out [64][10]. grid(10) block(256).
__global__ void __launch_bounds__(256) k8_fc3(const float* __restrict__ w,
                                              const float* __restrict__ bias,
                                              float* out, const float* ws) {
  const float* h7 = ws + OFF_H7 / 4;
  __shared__ float red[4][64];
  int lane = threadIdx.x & 63, wv = threadIdx.x >> 6;
  int o = blockIdx.x;
  float acc = 0.f;
  int i0 = wv * 21;
  #pragma unroll 7
  for (int i = i0; i < i0 + 21; ++i)
    acc = fmaf(h7[i * 64 + lane], w[o * 84 + i], acc);
  red[wv][lane] = acc;
  __syncthreads();
  if (threadIdx.x < 64) {
    float s = red[0][lane] + red[1][lane] + red[2][lane] + red[3][lane] + bias[o];
    out[lane * 10 + o] = s;
  }
}

extern "C" void kernel_launch(void* const* d_in, const int* in_sizes, int n_in,
                              void* d_out, int out_size, void* d_ws, size_t ws_size,
                              hipStream_t stream) {
  const float* x     = (const float*)d_in[0];
  const float* dw1_w = (const float*)d_in[1];
  const float* dw1_b = (const float*)d_in[2];
  const float* pc1_w = (const float*)d_in[3];
  const float* pc1_b = (const float*)d_in[4];
  const float* dw2_w = (const float*)d_in[5];
  const float* dw2_b = (const float*)d_in[6];
  const float* pc2_w = (const float*)d_in[7];
  const float* pc2_b = (const float*)d_in[8];
  const float* oo_w  = (const float*)d_in[9];
  const float* oo_b  = (const float*)d_in[10];
  const float* fc1_w = (const float*)d_in[11];
  const float* fc1_b = (const float*)d_in[12];
  const float* fc2_w = (const float*)d_in[13];
  const float* fc2_b = (const float*)d_in[14];
  const float* fc3_w = (const float*)d_in[15];
  const float* fc3_b = (const float*)d_in[16];
  float* ws = (float*)d_ws;
  float* out = (float*)d_out;

  hipLaunchKernelGGL(k0_setup, dim3(234), dim3(256), 0, stream, x, pc2_w, ws);
  hipLaunchKernelGGL(k1_dw1, dim3(882), dim3(64, 4), 0, stream, dw1_w, dw1_b, ws);
  hipLaunchKernelGGL(k2_pc1, dim3(625), dim3(64, 4), 0, stream, pc1_w, pc1_b, ws);
  hipLaunchKernelGGL(k3_dw2, dim3(1594), dim3(64, 4), 0, stream, dw2_w, dw2_b, ws);
  hipLaunchKernelGGL(k4_pc2, dim3(25, 67), dim3(64, 4), 0, stream, pc2_b, ws);
  hipLaunchKernelGGL(k5_oo, dim3(25, 25, 2), dim3(64, 4), 0, stream, oo_w, ws);
  hipLaunchKernelGGL(k6_fc1, dim3(30, 16), dim3(64, 4), 0, stream, fc1_w, oo_b, ws);
  hipLaunchKernelGGL(k7_fc2, dim3(84), dim3(256), 0, stream, fc2_w, fc1_b, fc2_b, ws);
  hipLaunchKernelGGL(k8_fc3, dim3(10), dim3(256), 0, stream, fc3_w, fc3_b, out, ws);
}